// Round 1
// baseline (440.512 us; speedup 1.0000x reference)
//
#include <hip/hip_runtime.h>

#define B_ 4096
#define T_ 512
#define F_ 8
#define H_ 16

typedef float f32x2 __attribute__((ext_vector_type(2)));

__device__ __forceinline__ f32x2 pkfma(f32x2 a, f32x2 b, f32x2 c) {
    return __builtin_elementwise_fma(a, b, c);
}

// tanh(x) = 2*sigmoid(2x) - 1
__device__ __forceinline__ float tanh_f(float v) {
    return 2.0f * __builtin_amdgcn_rcpf(1.0f + __expf(-2.0f * v)) - 1.0f;
}

// quad_perm DPP cross-lane (full-rate VALU, no LDS latency).
// CTRL 0xB1 = quad_perm[1,0,3,2] (xor 1), 0x4E = quad_perm[2,3,0,1] (xor 2).
template <int CTRL>
__device__ __forceinline__ float qperm(float v) {
    int i = __builtin_bit_cast(int, v);
    int rr = __builtin_amdgcn_update_dpp(i, i, CTRL, 0xF, 0xF, false);
    return __builtin_bit_cast(float, rr);
}

// Layout: 64 lanes per batch chain (1 chain per wave), 4 chains per 256-thread
// block, 1024 blocks -> 4096 waves -> 4 waves/SIMD (vs 2 before).
// Lane l owns gate row r = (l&3)*16 + (l>>2): the 4 gates (i,f,g,o) of hidden
// unit j = l>>2 live in the lane quad {4j..4j+3}, so the gate exchange is
// quad_perm DPP (VALU) instead of ds_swizzle (LDS). Only l&3==0 lanes combine
// gates correctly; other lanes compute bounded garbage that is never read.
// h broadcast: l&3==0 lanes write hbuf[ch][j]; all lanes reload as 4x b128.
__global__ __launch_bounds__(256, 4) void lstm_ae_kernel(
    const float* __restrict__ x,
    const float* __restrict__ eWih, const float* __restrict__ eWhh,
    const float* __restrict__ ebih, const float* __restrict__ ebhh,
    const float* __restrict__ dWih, const float* __restrict__ dWhh,
    const float* __restrict__ dbih, const float* __restrict__ dbhh,
    const float* __restrict__ oW,   const float* __restrict__ ob,
    float* __restrict__ out)
{
    const int tid = threadIdx.x;
    const int ch  = tid >> 6;        // chain (wave) within block, 0..3
    const int l   = tid & 63;        // lane within chain
    const int g   = l & 3;           // gate index: 0=i,1=f,2=g,3=o
    const int j   = l >> 2;          // hidden unit 0..15
    const int r   = g * 16 + j;      // gate row in the 4H weight matrices
    const int b   = blockIdx.x * 4 + ch;

    __shared__ __align__(16) float hbuf[4][16];
    __shared__ __align__(16) float xsh[4][256];

    const bool g0 = (g == 0);
    const float s1 = (g == 2) ? 2.0f : 1.0f;   // tanh rows get 2*sig(2x)-1
    const float m1 = (g == 2) ? 2.0f : 1.0f;
    const float c1 = (g == 2) ? -1.0f : 0.0f;

    // ---------------- encoder weights (registers, packed pairs) -----------
    f32x2 wh[8], wi[4];
#pragma unroll
    for (int k = 0; k < 16; k += 4) {
        float4 v = *(const float4*)(eWhh + r * 16 + k);
        wh[k/2]   = f32x2{v.x, v.y}; wh[k/2+1] = f32x2{v.z, v.w};
    }
#pragma unroll
    for (int k = 0; k < 8; k += 4) {
        float4 v = *(const float4*)(eWih + r * 8 + k);
        wi[k/2]   = f32x2{v.x, v.y}; wi[k/2+1] = f32x2{v.z, v.w};
    }
    const float bias = ebih[r] + ebhh[r];

    float c = 0.0f;
    f32x2 hb[8];
#pragma unroll
    for (int p = 0; p < 8; ++p) hb[p] = f32x2{0.0f, 0.0f};
    if (l < 16) hbuf[ch][l] = 0.0f;
    __builtin_amdgcn_wave_barrier();

    const float* xb = x + (size_t)b * (T_ * F_);
    float4 nx = *(const float4*)(xb + l * 4);   // prefetch chunk 0

    // ---------------- encoder ----------------
    for (int c0 = 0; c0 < T_; c0 += 32) {
        __builtin_amdgcn_wave_barrier();
        *(float4*)&xsh[ch][l * 4] = nx;          // 64 lanes x 16B = 32 steps
        __builtin_amdgcn_wave_barrier();
        if (c0 + 32 < T_)                        // prefetch next chunk: the
            nx = *(const float4*)(xb + (c0 + 32) * F_ + l * 4); // vmcnt wait
                                                 // hides under 32 steps
        for (int s = 0; s < 32; ++s) {
            float4 u0 = *(const float4*)&xsh[ch][s * F_];
            float4 u1 = *(const float4*)&xsh[ch][s * F_ + 4];

            f32x2 aa = f32x2{bias, 0.0f}, ab = f32x2{0.0f, 0.0f};
            aa = pkfma(wi[0], f32x2{u0.x, u0.y}, aa);
            ab = pkfma(wi[1], f32x2{u0.z, u0.w}, ab);
            aa = pkfma(wi[2], f32x2{u1.x, u1.y}, aa);
            ab = pkfma(wi[3], f32x2{u1.z, u1.w}, ab);
#pragma unroll
            for (int p = 0; p < 8; p += 2) {
                aa = pkfma(wh[p],   hb[p],   aa);
                ab = pkfma(wh[p+1], hb[p+1], ab);
            }
            f32x2 t = aa + ab;
            const float acc = t.x + t.y;

            // one activation per lane (own row), then quad DPP exchange
            const float a  = m1 * __builtin_amdgcn_rcpf(1.0f + __expf(-s1 * acc)) + c1;
            const float e1 = qperm<0xB1>(a);     // lane^1: f (for g==0 lanes)
            const float e2 = qperm<0x4E>(a);     // lane^2: g
            const float e3 = qperm<0xB1>(e2);    // lane^3: o
            c = e1 * c + a * e2;                 // f*c + i*g  (valid in g==0)
            const float h = e3 * tanh_f(c);      // o*tanh(c)

            __builtin_amdgcn_wave_barrier();
            if (g0) hbuf[ch][j] = h;
            __builtin_amdgcn_wave_barrier();
            float4 q0 = *(const float4*)&hbuf[ch][0];
            float4 q1 = *(const float4*)&hbuf[ch][4];
            float4 q2 = *(const float4*)&hbuf[ch][8];
            float4 q3 = *(const float4*)&hbuf[ch][12];
            hb[0] = f32x2{q0.x, q0.y}; hb[1] = f32x2{q0.z, q0.w};
            hb[2] = f32x2{q1.x, q1.y}; hb[3] = f32x2{q1.z, q1.w};
            hb[4] = f32x2{q2.x, q2.y}; hb[5] = f32x2{q2.z, q2.w};
            hb[6] = f32x2{q3.x, q3.y}; hb[7] = f32x2{q3.z, q3.w};
        }
    }

    // ---------------- decoder weights + constant input projection ----------
    f32x2 wd[8], wo2[8];
    float xp;
    {
        f32x2 pa = f32x2{dbih[r] + dbhh[r], 0.0f}, pb = f32x2{0.0f, 0.0f};
#pragma unroll
        for (int k = 0; k < 16; k += 4) {
            float4 v = *(const float4*)(dWih + r * 16 + k);
            pa = pkfma(f32x2{v.x, v.y}, hb[k/2],   pa);
            pb = pkfma(f32x2{v.z, v.w}, hb[k/2+1], pb);
        }
        f32x2 t = pa + pb; xp = t.x + t.y;
#pragma unroll
        for (int k = 0; k < 16; k += 4) {
            float4 v = *(const float4*)(dWhh + r * 16 + k);
            wd[k/2]   = f32x2{v.x, v.y}; wd[k/2+1] = f32x2{v.z, v.w};
        }
        const int fo = l & 7;
#pragma unroll
        for (int k = 0; k < 16; k += 4) {
            float4 v = *(const float4*)(oW + fo * 16 + k);
            wo2[k/2]   = f32x2{v.x, v.y}; wo2[k/2+1] = f32x2{v.z, v.w};
        }
    }
    const float obv = ob[l & 7];

    c = 0.0f;
#pragma unroll
    for (int p = 0; p < 8; ++p) hb[p] = f32x2{0.0f, 0.0f};
    __builtin_amdgcn_wave_barrier();

    float* outp = out + (size_t)b * (T_ * F_);

    // ---------------- decoder + fused output projection ----------------
    for (int t = 0; t < T_; ++t) {
        f32x2 aa = f32x2{xp, 0.0f}, ab = f32x2{0.0f, 0.0f};
#pragma unroll
        for (int p = 0; p < 8; p += 2) {
            aa = pkfma(wd[p],   hb[p],   aa);
            ab = pkfma(wd[p+1], hb[p+1], ab);
        }
        f32x2 tt = aa + ab;
        const float acc = tt.x + tt.y;

        const float a  = m1 * __builtin_amdgcn_rcpf(1.0f + __expf(-s1 * acc)) + c1;
        const float e1 = qperm<0xB1>(a);
        const float e2 = qperm<0x4E>(a);
        const float e3 = qperm<0xB1>(e2);
        c = e1 * c + a * e2;
        const float h = e3 * tanh_f(c);

        __builtin_amdgcn_wave_barrier();
        if (g0) hbuf[ch][j] = h;
        __builtin_amdgcn_wave_barrier();
        float4 q0 = *(const float4*)&hbuf[ch][0];
        float4 q1 = *(const float4*)&hbuf[ch][4];
        float4 q2 = *(const float4*)&hbuf[ch][8];
        float4 q3 = *(const float4*)&hbuf[ch][12];
        hb[0] = f32x2{q0.x, q0.y}; hb[1] = f32x2{q0.z, q0.w};
        hb[2] = f32x2{q1.x, q1.y}; hb[3] = f32x2{q1.z, q1.w};
        hb[4] = f32x2{q2.x, q2.y}; hb[5] = f32x2{q2.z, q2.w};
        hb[6] = f32x2{q3.x, q3.y}; hb[7] = f32x2{q3.z, q3.w};

        // output projection from the just-updated h (feature l&7, x8 redundant)
        f32x2 oaa = f32x2{obv, 0.0f}, oab = f32x2{0.0f, 0.0f};
#pragma unroll
        for (int p = 0; p < 8; p += 2) {
            oaa = pkfma(wo2[p],   hb[p],   oaa);
            oab = pkfma(wo2[p+1], hb[p+1], oab);
        }
        f32x2 to = oaa + oab;
        if (l < 8) outp[t * F_ + l] = to.x + to.y;
    }
}

extern "C" void kernel_launch(void* const* d_in, const int* in_sizes, int n_in,
                              void* d_out, int out_size, void* d_ws, size_t ws_size,
                              hipStream_t stream) {
    (void)in_sizes; (void)n_in; (void)d_ws; (void)ws_size; (void)out_size;
    lstm_ae_kernel<<<dim3(B_ / 4), dim3(256), 0, stream>>>(
        (const float*)d_in[0],
        (const float*)d_in[1], (const float*)d_in[2],
        (const float*)d_in[3], (const float*)d_in[4],
        (const float*)d_in[5], (const float*)d_in[6],
        (const float*)d_in[7], (const float*)d_in[8],
        (const float*)d_in[9], (const float*)d_in[10],
        (float*)d_out);
}

// Round 2
// 427.823 us; speedup vs baseline: 1.0297x; 1.0297x over previous
//
#include <hip/hip_runtime.h>

#define B_ 4096
#define T_ 512
#define F_ 8
#define H_ 16

typedef float f32x2 __attribute__((ext_vector_type(2)));

__device__ __forceinline__ f32x2 pkfma(f32x2 a, f32x2 b, f32x2 c) {
    return __builtin_elementwise_fma(a, b, c);
}

#define LOG2E 1.442695041f
#define N2LOG2E (-2.0f * 1.442695041f)

// quad_perm DPP cross-lane (full-rate VALU, no LDS latency).
// 0xB1 = quad_perm[1,0,3,2] (xor 1), 0x4E = quad_perm[2,3,0,1] (xor 2),
// 0x1B = quad_perm[3,2,1,0] (xor 3).
template <int CTRL>
__device__ __forceinline__ float qperm(float v) {
    int i = __builtin_bit_cast(int, v);
    int rr = __builtin_amdgcn_update_dpp(i, i, CTRL, 0xF, 0xF, false);
    return __builtin_bit_cast(float, rr);
}

// Layout: 64 lanes per batch chain (1 chain per wave), 4 chains per 256-thread
// block, 1024 blocks -> 4096 waves -> 4 waves/SIMD.
// Lane l owns gate row r = (l&3)*16 + (l>>2): the 4 gates (i,f,g,o) of hidden
// unit j = l>>2 live in the lane quad {4j..4j+3}; gate exchange is quad_perm
// DPP. Only l&3==0 lanes combine gates correctly; other lanes compute bounded
// garbage (|c| grows at most linearly, no NaN) that is never read.
// All LDS IO is f32x2 so pk-operands land in even-aligned pairs (no repacks).
__global__ __launch_bounds__(256, 4) void lstm_ae_kernel(
    const float* __restrict__ x,
    const float* __restrict__ eWih, const float* __restrict__ eWhh,
    const float* __restrict__ ebih, const float* __restrict__ ebhh,
    const float* __restrict__ dWih, const float* __restrict__ dWhh,
    const float* __restrict__ dbih, const float* __restrict__ dbhh,
    const float* __restrict__ oW,   const float* __restrict__ ob,
    float* __restrict__ out)
{
    const int tid = threadIdx.x;
    const int ch  = tid >> 6;        // chain (wave) within block, 0..3
    const int l   = tid & 63;        // lane within chain
    const int g   = l & 3;           // gate index: 0=i,1=f,2=g,3=o
    const int j   = l >> 2;          // hidden unit 0..15
    const int r   = g * 16 + j;      // gate row in the 4H weight matrices
    const int b   = blockIdx.x * 4 + ch;

    __shared__ __align__(16) f32x2 hbuf2[4][8];
    __shared__ __align__(16) f32x2 xsh2[4][128];

    const bool g0 = (g == 0);
    // activation: a = m1 * rcp(1 + exp2(ns1*acc)) + c1  (log2e pre-folded)
    const float ns1 = (g == 2) ? N2LOG2E : -LOG2E;
    const float m1  = (g == 2) ? 2.0f : 1.0f;
    const float c1  = (g == 2) ? -1.0f : 0.0f;
    const f32x2 zero2 = {0.0f, 0.0f};

    // ---------------- encoder weights (registers, packed pairs) -----------
    f32x2 wh[8], wi[4];
    {
        const f32x2* w2 = (const f32x2*)(eWhh + r * 16);
#pragma unroll
        for (int p = 0; p < 8; ++p) wh[p] = w2[p];
        const f32x2* wi2 = (const f32x2*)(eWih + r * 8);
#pragma unroll
        for (int p = 0; p < 4; ++p) wi[p] = wi2[p];
    }
    const f32x2 bias2 = {ebih[r] + ebhh[r], 0.0f};

    float c = 0.0f;
    f32x2 hb[8];
#pragma unroll
    for (int p = 0; p < 8; ++p) hb[p] = zero2;
    if (l < 8) hbuf2[ch][l] = zero2;
    __builtin_amdgcn_wave_barrier();

    const float* xb = x + (size_t)b * (T_ * F_);
    float4 nx = *(const float4*)(xb + l * 4);   // prefetch chunk 0

    // ---------------- encoder ----------------
    for (int c0 = 0; c0 < T_; c0 += 32) {
        __builtin_amdgcn_wave_barrier();
        *(float4*)&xsh2[ch][l * 2] = nx;         // 64 lanes x 16B = 32 steps
        __builtin_amdgcn_wave_barrier();
        if (c0 + 32 < T_)                        // vmcnt wait hides under the
            nx = *(const float4*)(xb + (c0 + 32) * F_ + l * 4);  // 32 steps
        for (int s = 0; s < 32; ++s) {
            f32x2 x0 = xsh2[ch][s * 4 + 0];
            f32x2 x1 = xsh2[ch][s * 4 + 1];
            f32x2 x2 = xsh2[ch][s * 4 + 2];
            f32x2 x3 = xsh2[ch][s * 4 + 3];

            f32x2 aa = pkfma(wi[0], x0, bias2);
            f32x2 ab = pkfma(wi[1], x1, zero2);
            aa = pkfma(wi[2], x2, aa);
            ab = pkfma(wi[3], x3, ab);
#pragma unroll
            for (int p = 0; p < 8; p += 2) {
                aa = pkfma(wh[p],   hb[p],   aa);
                ab = pkfma(wh[p+1], hb[p+1], ab);
            }
            f32x2 t = aa + ab;
            const float acc = t.x + t.y;

            // one activation per lane (own row), then quad DPP exchange
            const float a = __builtin_fmaf(
                m1, __builtin_amdgcn_rcpf(1.0f + __builtin_amdgcn_exp2f(ns1 * acc)), c1);
            const float e1 = qperm<0xB1>(a);     // lane^1: f (for g==0 lanes)
            const float e2 = qperm<0x4E>(a);     // lane^2: g
            const float e3 = qperm<0x1B>(a);     // lane^3: o
            c = __builtin_fmaf(e1, c, a * e2);   // f*c + i*g  (valid in g==0)
            // h = o*tanh(c) = fma(2o, rcp(1+exp2(-2*log2e*c)), -o)
            const float rt = __builtin_amdgcn_rcpf(
                1.0f + __builtin_amdgcn_exp2f(N2LOG2E * c));
            const float h = __builtin_fmaf(e3 + e3, rt, -e3);

            __builtin_amdgcn_wave_barrier();
            if (g0) ((float*)&hbuf2[ch][0])[j] = h;
            __builtin_amdgcn_wave_barrier();
#pragma unroll
            for (int p = 0; p < 8; ++p) hb[p] = hbuf2[ch][p];
        }
    }

    // ---------------- decoder weights + constant input projection ----------
    f32x2 wd[8], wo2[8];
    f32x2 xp2;
    {
        f32x2 pa = {dbih[r] + dbhh[r], 0.0f};
        f32x2 pb = zero2;
        const f32x2* wih2 = (const f32x2*)(dWih + r * 16);
#pragma unroll
        for (int p = 0; p < 8; p += 2) {
            pa = pkfma(wih2[p],   hb[p],   pa);
            pb = pkfma(wih2[p+1], hb[p+1], pb);
        }
        f32x2 t = pa + pb;
        xp2 = f32x2{t.x + t.y, 0.0f};
        const f32x2* whh2 = (const f32x2*)(dWhh + r * 16);
#pragma unroll
        for (int p = 0; p < 8; ++p) wd[p] = whh2[p];
        const f32x2* wo = (const f32x2*)(oW + (l & 7) * 16);
#pragma unroll
        for (int p = 0; p < 8; ++p) wo2[p] = wo[p];
    }
    const f32x2 ob2 = {ob[l & 7], 0.0f};
    const bool l8 = (l < 8);

    c = 0.0f;
#pragma unroll
    for (int p = 0; p < 8; ++p) hb[p] = zero2;
    __builtin_amdgcn_wave_barrier();

    float* outp = out + (size_t)b * (T_ * F_);

    // ---------------- decoder + fused output projection ----------------
    for (int t = 0; t < T_; ++t) {
        f32x2 aa = pkfma(wd[0], hb[0], xp2);
        f32x2 ab = pkfma(wd[1], hb[1], zero2);
#pragma unroll
        for (int p = 2; p < 8; p += 2) {
            aa = pkfma(wd[p],   hb[p],   aa);
            ab = pkfma(wd[p+1], hb[p+1], ab);
        }
        f32x2 tt = aa + ab;
        const float acc = tt.x + tt.y;

        const float a = __builtin_fmaf(
            m1, __builtin_amdgcn_rcpf(1.0f + __builtin_amdgcn_exp2f(ns1 * acc)), c1);
        const float e1 = qperm<0xB1>(a);
        const float e2 = qperm<0x4E>(a);
        const float e3 = qperm<0x1B>(a);
        c = __builtin_fmaf(e1, c, a * e2);
        const float rt = __builtin_amdgcn_rcpf(
            1.0f + __builtin_amdgcn_exp2f(N2LOG2E * c));
        const float h = __builtin_fmaf(e3 + e3, rt, -e3);

        __builtin_amdgcn_wave_barrier();
        if (g0) ((float*)&hbuf2[ch][0])[j] = h;
        __builtin_amdgcn_wave_barrier();
#pragma unroll
        for (int p = 0; p < 8; ++p) hb[p] = hbuf2[ch][p];

        // output projection from the just-updated h (feature l&7, x8 redundant)
        f32x2 oa = pkfma(wo2[0], hb[0], ob2);
        f32x2 obb = pkfma(wo2[1], hb[1], zero2);
#pragma unroll
        for (int p = 2; p < 8; p += 2) {
            oa  = pkfma(wo2[p],   hb[p],   oa);
            obb = pkfma(wo2[p+1], hb[p+1], obb);
        }
        f32x2 to = oa + obb;
        if (l8) outp[t * F_ + l] = to.x + to.y;
    }
}

extern "C" void kernel_launch(void* const* d_in, const int* in_sizes, int n_in,
                              void* d_out, int out_size, void* d_ws, size_t ws_size,
                              hipStream_t stream) {
    (void)in_sizes; (void)n_in; (void)d_ws; (void)ws_size; (void)out_size;
    lstm_ae_kernel<<<dim3(B_ / 4), dim3(256), 0, stream>>>(
        (const float*)d_in[0],
        (const float*)d_in[1], (const float*)d_in[2],
        (const float*)d_in[3], (const float*)d_in[4],
        (const float*)d_in[5], (const float*)d_in[6],
        (const float*)d_in[7], (const float*)d_in[8],
        (const float*)d_in[9], (const float*)d_in[10],
        (float*)d_out);
}